// Round 4
// baseline (134.237 us; speedup 1.0000x reference)
//
#include <hip/hip_runtime.h>
#include <hip/hip_bf16.h>

typedef __attribute__((ext_vector_type(8))) short short8;   // 8 bf16 (4 VGPRs)
typedef __attribute__((ext_vector_type(4))) float float4v;  // 4 fp32 acc

#define C2EXP 2.8853900817779268f  /* 2*log2(e): exp(2s) = exp2(C2EXP*s), tau=0.5 */

#if __has_builtin(__builtin_amdgcn_exp2f)
#define EXP2F(x) __builtin_amdgcn_exp2f(x)   /* raw v_exp_f32; safe: args in [-2.9,2.9] */
#else
#define EXP2F(x) exp2f(x)
#endif

__device__ __forceinline__ float bf16lo(unsigned int u){ return __uint_as_float((u & 0xFFFFu) << 16); }
__device__ __forceinline__ float bf16hi(unsigned int u){ return __uint_as_float(u & 0xFFFF0000u); }

// K1 (fused prep): one wave per group.
//  - normalize the group's rows (fp32 norm, clamp 1e-8), round to bf16, store zb packed
//  - zero t for the group's rows; block 0 zeros out
//  - pos[i] = sum_{j in group, j != i} exp(2*cos), self[i] = exp(2*z_i.z_i)
//    (fp32 dots of the SAME bf16-rounded z used by k_gram -> consistent with MFMA sums)
__global__ void k_prep(const float* __restrict__ f, const int* __restrict__ nc,
                       unsigned int* __restrict__ zb, float* __restrict__ t,
                       float* __restrict__ possum, float* __restrict__ selfs,
                       float* __restrict__ out, int G){
    int g = blockIdx.x, lane = threadIdx.x;
    if (g == 0 && lane == 0) out[0] = 0.0f;
    // group start = sum of nc[0..g)
    int st = 0;
    for (int i = lane; i < g; i += 64) st += nc[i];
    #pragma unroll
    for (int m = 1; m < 64; m <<= 1) st += __shfl_xor(st, m);
    int c = nc[g];
    for (int i = lane; i < c; i += 64) t[st + i] = 0.0f;

    for (int r = 0; r < c; r++){
        const float2* fr = (const float2*)(f + (size_t)(st + r) * 128);
        float2 v = fr[lane];
        float ss = v.x * v.x + v.y * v.y;
        #pragma unroll
        for (int m = 1; m < 64; m <<= 1) ss += __shfl_xor(ss, m);
        float scale = 1.0f / fmaxf(sqrtf(ss), 1e-8f);
        __hip_bfloat16 h0 = __float2bfloat16(v.x * scale);
        __hip_bfloat16 h1 = __float2bfloat16(v.y * scale);
        unsigned short b0, b1;
        __builtin_memcpy(&b0, &h0, 2);
        __builtin_memcpy(&b1, &h1, 2);
        zb[(st + r) * 64 + lane] = (unsigned int)b0 | ((unsigned int)b1 << 16);
    }
    // small Gram over the group's own rows (reload own-lane zb: same-thread RAW, safe)
    for (int a = 0; a < c; a++){
        unsigned int ua = zb[(st + a) * 64 + lane];
        float a0 = bf16lo(ua), a1 = bf16hi(ua);
        float pacc = 0.0f;
        for (int b = 0; b < c; b++){
            unsigned int ub = zb[(st + b) * 64 + lane];
            float s = a0 * bf16lo(ub) + a1 * bf16hi(ub);
            #pragma unroll
            for (int m = 1; m < 64; m <<= 1) s += __shfl_xor(s, m);
            float e = EXP2F(C2EXP * s);
            if (b == a){ if (lane == 0) selfs[st + a] = e; }
            else pacc += e;
        }
        if (lane == 0) possum[st + a] = pacc;
    }
}

// K2: barrier-free Gram row-sums, occupancy-first.
// Grid (N/256, N/256); block = 4 waves sharing one 256-col chunk (B reused 4x via L1).
// Wave = 64 rows (A fragments resident in regs, full K=128) x 4 j-tiles of 64 cols.
// launch_bounds(...,3) caps VGPRs ~168 -> 3 blocks/CU = 3 waves/SIMD for latency hiding.
// Fragment: lane holds z[base+(lane&15)][ki*32 + (lane>>4)*8 .. +7]
__global__ __launch_bounds__(256, 3) void k_gram(const unsigned short* __restrict__ z,
                                                 float* __restrict__ t, int N){
    int tid  = threadIdx.x;
    int lane = tid & 63, w = tid >> 6;
    int quad = lane >> 4, l15 = lane & 15;
    int r0 = blockIdx.x * 256 + w * 64;
    int c0 = blockIdx.y * 256;
    size_t lq = (size_t)l15 * 128 + quad * 8;

    // A fragments: 64 rows x full K, held for the whole kernel (16 x 16B loads)
    const unsigned short* za = z + (size_t)r0 * 128;
    short8 af[4][4];
    #pragma unroll
    for (int mi = 0; mi < 4; mi++)
        #pragma unroll
        for (int ki = 0; ki < 4; ki++)
            af[mi][ki] = *(const short8*)&za[(size_t)(mi * 16) * 128 + lq + ki * 32];

    float ts[4][4];
    #pragma unroll
    for (int mi = 0; mi < 4; mi++)
        #pragma unroll
        for (int r = 0; r < 4; r++) ts[mi][r] = 0.0f;

    #pragma unroll 1
    for (int jt = 0; jt < 4; jt++){
        const unsigned short* zbp = z + (size_t)(c0 + jt * 64) * 128 + lq;
        float4v acc[4][4];
        #pragma unroll
        for (int mi = 0; mi < 4; mi++)
            #pragma unroll
            for (int ni = 0; ni < 4; ni++)
                acc[mi][ni] = (float4v){0.0f, 0.0f, 0.0f, 0.0f};

        #pragma unroll
        for (int ki = 0; ki < 4; ki++){
            short8 bfr[4];
            #pragma unroll
            for (int ni = 0; ni < 4; ni++)
                bfr[ni] = *(const short8*)&zbp[(size_t)(ni * 16) * 128 + ki * 32];
            #pragma unroll
            for (int mi = 0; mi < 4; mi++)
                #pragma unroll
                for (int ni = 0; ni < 4; ni++)
                    acc[mi][ni] = __builtin_amdgcn_mfma_f32_16x16x32_bf16(
                        af[mi][ki], bfr[ni], acc[mi][ni], 0, 0, 0);
        }
        // epilogue: e = exp(2s); C layout: col = lane&15, row_local = mi*16 + quad*4 + r
        #pragma unroll
        for (int mi = 0; mi < 4; mi++)
            #pragma unroll
            for (int ni = 0; ni < 4; ni++)
                #pragma unroll
                for (int r = 0; r < 4; r++)
                    ts[mi][r] += EXP2F(C2EXP * acc[mi][ni][r]);
    }

    // reduce across the 16 column-lanes (same quad), one atomic per row
    #pragma unroll
    for (int mi = 0; mi < 4; mi++)
        #pragma unroll
        for (int r = 0; r < 4; r++){
            float v = ts[mi][r];
            v += __shfl_xor(v, 1);
            v += __shfl_xor(v, 2);
            v += __shfl_xor(v, 4);
            v += __shfl_xor(v, 8);
            ts[mi][r] = v;
        }
    if (l15 == 0){
        #pragma unroll
        for (int mi = 0; mi < 4; mi++)
            #pragma unroll
            for (int r = 0; r < 4; r++)
                atomicAdd(&t[r0 + mi * 16 + quad * 4 + r], ts[mi][r]);
    }
}

// K3: loss = mean over rows of log(neg) - log(pos); neg = t - pos - self.
__global__ void k_final(const float* __restrict__ t, const float* __restrict__ possum,
                        const float* __restrict__ selfs, float* __restrict__ out, int N){
    int tid = threadIdx.x;
    int gid = blockIdx.x * 256 + tid;
    float s = 0.0f;
    if (gid < N){
        float p = possum[gid];
        float n = t[gid] - p - selfs[gid];
        s = logf(n) - logf(p);
    }
    #pragma unroll
    for (int m = 1; m < 64; m <<= 1) s += __shfl_xor(s, m);
    __shared__ float red[4];
    if ((tid & 63) == 0) red[tid >> 6] = s;
    __syncthreads();
    if (tid == 0) atomicAdd(out, (red[0] + red[1] + red[2] + red[3]) / (float)N);
}

extern "C" void kernel_launch(void* const* d_in, const int* in_sizes, int n_in,
                              void* d_out, int out_size, void* d_ws, size_t ws_size,
                              hipStream_t stream){
    const float* f  = (const float*)d_in[0];
    const int*   nc = (const int*)d_in[1];
    int N = in_sizes[0] / 128;   // 8192
    int G = in_sizes[1];         // 2048

    unsigned int* zb = (unsigned int*)d_ws;                       // N*256 bytes bf16 z
    float* t     = (float*)((char*)d_ws + (size_t)N * 256);       // N fp32
    float* pos   = t + N;
    float* selfs = pos + N;
    float* out   = (float*)d_out;

    k_prep<<<G, 64, 0, stream>>>(f, nc, zb, t, pos, selfs, out, G);
    dim3 grid(N / 256, N / 256);
    k_gram<<<grid, 256, 0, stream>>>((const unsigned short*)zb, t, N);
    k_final<<<(N + 255) / 256, 256, 0, stream>>>(t, pos, selfs, out, N);
}

// Round 5
// 113.427 us; speedup vs baseline: 1.1835x; 1.1835x over previous
//
#include <hip/hip_runtime.h>
#include <hip/hip_bf16.h>

typedef __attribute__((ext_vector_type(8))) short short8;   // 8 bf16 (4 VGPRs)
typedef __attribute__((ext_vector_type(4))) float float4v;  // 4 fp32 acc

// z is pre-scaled by sqrt(2*log2(e)), so MFMA dot = 2*log2(e)*cos and
// exp(2*cos) = exp2(dot) directly — no per-element multiply in the epilogue.
#define ZSCALE 1.6986436f

__device__ __forceinline__ float bf16lo(unsigned int u){ return __uint_as_float((u & 0xFFFFu) << 16); }
__device__ __forceinline__ float bf16hi(unsigned int u){ return __uint_as_float(u & 0xFFFF0000u); }

// K1 (fused prep): one wave per group.
//  - normalize group rows (fp32 norm, clamp 1e-8), scale by ZSCALE, round bf16, store
//  - zero t for the group's rows; group 0 zeros out
//  - pos[i] = sum_{j in group, j!=i} exp2(dot), self[i] = exp2(z_i.z_i)  (scaled dots,
//    fp32, same bf16 z as k_gram -> consistent with the MFMA sums)
__global__ void k_prep(const float* __restrict__ f, const int* __restrict__ nc,
                       unsigned int* __restrict__ zb, float* __restrict__ t,
                       float* __restrict__ possum, float* __restrict__ selfs,
                       float* __restrict__ out, int G){
    int g = blockIdx.x, lane = threadIdx.x;
    if (g == 0 && lane == 0) out[0] = 0.0f;
    int st = 0;
    for (int i = lane; i < g; i += 64) st += nc[i];
    #pragma unroll
    for (int m = 1; m < 64; m <<= 1) st += __shfl_xor(st, m);
    int c = nc[g];
    for (int i = lane; i < c; i += 64) t[st + i] = 0.0f;

    for (int r = 0; r < c; r++){
        const float2* fr = (const float2*)(f + (size_t)(st + r) * 128);
        float2 v = fr[lane];
        float ss = v.x * v.x + v.y * v.y;
        #pragma unroll
        for (int m = 1; m < 64; m <<= 1) ss += __shfl_xor(ss, m);
        float scale = ZSCALE / fmaxf(sqrtf(ss), 1e-8f);
        __hip_bfloat16 h0 = __float2bfloat16(v.x * scale);
        __hip_bfloat16 h1 = __float2bfloat16(v.y * scale);
        unsigned short b0, b1;
        __builtin_memcpy(&b0, &h0, 2);
        __builtin_memcpy(&b1, &h1, 2);
        zb[(st + r) * 64 + lane] = (unsigned int)b0 | ((unsigned int)b1 << 16);
    }
    for (int a = 0; a < c; a++){
        unsigned int ua = zb[(st + a) * 64 + lane];
        float a0 = bf16lo(ua), a1 = bf16hi(ua);
        float pacc = 0.0f;
        for (int b = 0; b < c; b++){
            unsigned int ub = zb[(st + b) * 64 + lane];
            float s = a0 * bf16lo(ub) + a1 * bf16hi(ub);
            #pragma unroll
            for (int m = 1; m < 64; m <<= 1) s += __shfl_xor(s, m);
            float e = exp2f(s);
            if (b == a){ if (lane == 0) selfs[st + a] = e; }
            else pacc += e;
        }
        if (lane == 0) possum[st + a] = pacc;
    }
}

// K2: barrier-free Gram row-sums, occupancy-first ni-strip structure.
// Grid (N/256, N/256); block = 4 independent waves; wave = 64 rows x 256 cols,
// processed as 16 strips of 16 cols. Per strip: 4 x 16B B-loads (immediate
// offsets off one pointer, bumped per strip) -> 16 MFMA -> 16 exp2+add.
// acc is only 16 VGPRs (vs 64 for full 64x64 tiles) -> target <=128 total
// for 4 waves/SIMD. A fragments (64 regs) stay resident all kernel.
// Fragment: lane holds z[base+(lane&15)][ki*32 + (lane>>4)*8 .. +7]
__global__ __launch_bounds__(256) void k_gram(const unsigned short* __restrict__ z,
                                              float* __restrict__ t, int N){
    int tid  = threadIdx.x;
    int lane = tid & 63, w = tid >> 6;
    int quad = lane >> 4, l15 = lane & 15;
    int r0 = blockIdx.x * 256 + w * 64;
    int c0 = blockIdx.y * 256;
    size_t lq = (size_t)l15 * 128 + quad * 8;

    const unsigned short* za = z + (size_t)r0 * 128;
    short8 af[4][4];
    #pragma unroll
    for (int mi = 0; mi < 4; mi++)
        #pragma unroll
        for (int ki = 0; ki < 4; ki++)
            af[mi][ki] = *(const short8*)&za[(size_t)(mi * 16) * 128 + lq + ki * 32];

    float ts[4][4];
    #pragma unroll
    for (int mi = 0; mi < 4; mi++)
        #pragma unroll
        for (int r = 0; r < 4; r++) ts[mi][r] = 0.0f;

    const unsigned short* zp = z + (size_t)c0 * 128 + lq;
    #pragma unroll 1
    for (int st = 0; st < 16; st++){
        short8 b0 = *(const short8*)(zp);
        short8 b1 = *(const short8*)(zp + 32);
        short8 b2 = *(const short8*)(zp + 64);
        short8 b3 = *(const short8*)(zp + 96);
        float4v acc[4];
        #pragma unroll
        for (int mi = 0; mi < 4; mi++) acc[mi] = (float4v){0.0f, 0.0f, 0.0f, 0.0f};
        #pragma unroll
        for (int mi = 0; mi < 4; mi++)
            acc[mi] = __builtin_amdgcn_mfma_f32_16x16x32_bf16(af[mi][0], b0, acc[mi], 0, 0, 0);
        #pragma unroll
        for (int mi = 0; mi < 4; mi++)
            acc[mi] = __builtin_amdgcn_mfma_f32_16x16x32_bf16(af[mi][1], b1, acc[mi], 0, 0, 0);
        #pragma unroll
        for (int mi = 0; mi < 4; mi++)
            acc[mi] = __builtin_amdgcn_mfma_f32_16x16x32_bf16(af[mi][2], b2, acc[mi], 0, 0, 0);
        #pragma unroll
        for (int mi = 0; mi < 4; mi++)
            acc[mi] = __builtin_amdgcn_mfma_f32_16x16x32_bf16(af[mi][3], b3, acc[mi], 0, 0, 0);
        // epilogue: dot is already the exp2 argument (pre-scaled z).
        // C layout: col = lane&15 (strip-local), row_local = mi*16 + quad*4 + r
        #pragma unroll
        for (int mi = 0; mi < 4; mi++)
            #pragma unroll
            for (int r = 0; r < 4; r++)
                ts[mi][r] += exp2f(acc[mi][r]);
        zp += 16 * 128;   // next 16-col strip
    }

    // reduce across the 16 column-lanes (same quad), one atomic per row
    #pragma unroll
    for (int mi = 0; mi < 4; mi++)
        #pragma unroll
        for (int r = 0; r < 4; r++){
            float v = ts[mi][r];
            v += __shfl_xor(v, 1);
            v += __shfl_xor(v, 2);
            v += __shfl_xor(v, 4);
            v += __shfl_xor(v, 8);
            ts[mi][r] = v;
        }
    if (l15 == 0){
        #pragma unroll
        for (int mi = 0; mi < 4; mi++)
            #pragma unroll
            for (int r = 0; r < 4; r++)
                atomicAdd(&t[r0 + mi * 16 + quad * 4 + r], ts[mi][r]);
    }
}

// K3: loss = mean over rows of log(neg) - log(pos); neg = t - pos - self.
__global__ void k_final(const float* __restrict__ t, const float* __restrict__ possum,
                        const float* __restrict__ selfs, float* __restrict__ out, int N){
    int tid = threadIdx.x;
    int gid = blockIdx.x * 256 + tid;
    float s = 0.0f;
    if (gid < N){
        float p = possum[gid];
        float n = t[gid] - p - selfs[gid];
        s = logf(n) - logf(p);
    }
    #pragma unroll
    for (int m = 1; m < 64; m <<= 1) s += __shfl_xor(s, m);
    __shared__ float red[4];
    if ((tid & 63) == 0) red[tid >> 6] = s;
    __syncthreads();
    if (tid == 0) atomicAdd(out, (red[0] + red[1] + red[2] + red[3]) / (float)N);
}

extern "C" void kernel_launch(void* const* d_in, const int* in_sizes, int n_in,
                              void* d_out, int out_size, void* d_ws, size_t ws_size,
                              hipStream_t stream){
    const float* f  = (const float*)d_in[0];
    const int*   nc = (const int*)d_in[1];
    int N = in_sizes[0] / 128;   // 8192
    int G = in_sizes[1];         // 2048

    unsigned int* zb = (unsigned int*)d_ws;                       // N*256 bytes bf16 z (pre-scaled)
    float* t     = (float*)((char*)d_ws + (size_t)N * 256);       // N fp32
    float* pos   = t + N;
    float* selfs = pos + N;
    float* out   = (float*)d_out;

    k_prep<<<G, 64, 0, stream>>>(f, nc, zb, t, pos, selfs, out, G);
    dim3 grid(N / 256, N / 256);
    k_gram<<<grid, 256, 0, stream>>>((const unsigned short*)zb, t, N);
    k_final<<<(N + 255) / 256, 256, 0, stream>>>(t, pos, selfs, out, N);
}

// Round 6
// 109.754 us; speedup vs baseline: 1.2231x; 1.0335x over previous
//
#include <hip/hip_runtime.h>
#include <hip/hip_bf16.h>

typedef __attribute__((ext_vector_type(8))) short short8;   // 8 bf16 (4 VGPRs)
typedef __attribute__((ext_vector_type(4))) float float4v;  // 4 fp32 acc

// z is pre-scaled by sqrt(2*log2(e)), so MFMA dot = 2*log2(e)*cos and
// exp(2*cos/..) = exp2(dot) directly — no multiply in the epilogue.
#define ZSCALE 1.6986436f

__device__ __forceinline__ float bf16lo(unsigned int u){ return __uint_as_float((u & 0xFFFFu) << 16); }
__device__ __forceinline__ float bf16hi(unsigned int u){ return __uint_as_float(u & 0xFFFF0000u); }

// K1 (fused prep): one wave per group.
//  - group start via 4-wide unrolled strided scan of num_crops (general)
//  - normalize rows (fp32 norm, clamp 1e-8), scale ZSCALE, round bf16, store packed
//  - pos[i]/self[i] via fp32 dots of the SAME bf16 z (consistent with MFMA sums);
//    4 pair-dots share ONE 6-step shuffle reduction (float4 payload)
__global__ void k_prep(const float* __restrict__ f, const int* __restrict__ nc,
                       unsigned int* __restrict__ zb, float* __restrict__ t,
                       float* __restrict__ possum, float* __restrict__ selfs,
                       float* __restrict__ out, int G){
    int g = blockIdx.x, lane = threadIdx.x;
    if (g == 0 && lane == 0) out[0] = 0.0f;
    int st = 0;
    {
        int i = lane;
        for (; i + 192 < g; i += 256)
            st += nc[i] + nc[i + 64] + nc[i + 128] + nc[i + 192];
        for (; i < g; i += 64) st += nc[i];
    }
    #pragma unroll
    for (int m = 1; m < 64; m <<= 1) st += __shfl_xor(st, m);
    int c = nc[g];
    for (int i = lane; i < c; i += 64) t[st + i] = 0.0f;

    for (int r = 0; r < c; r++){
        const float2* fr = (const float2*)(f + (size_t)(st + r) * 128);
        float2 v = fr[lane];
        float ss = v.x * v.x + v.y * v.y;
        #pragma unroll
        for (int m = 1; m < 64; m <<= 1) ss += __shfl_xor(ss, m);
        float scale = ZSCALE / fmaxf(sqrtf(ss), 1e-8f);
        __hip_bfloat16 h0 = __float2bfloat16(v.x * scale);
        __hip_bfloat16 h1 = __float2bfloat16(v.y * scale);
        unsigned short b0, b1;
        __builtin_memcpy(&b0, &h0, 2);
        __builtin_memcpy(&b1, &h1, 2);
        zb[(st + r) * 64 + lane] = (unsigned int)b0 | ((unsigned int)b1 << 16);
    }
    for (int a = 0; a < c; a++){
        unsigned int ua = zb[(st + a) * 64 + lane];
        float a0 = bf16lo(ua), a1 = bf16hi(ua);
        float pacc = 0.0f;
        for (int bb = 0; bb < c; bb += 4){
            float s[4];
            #pragma unroll
            for (int u = 0; u < 4; u++){
                int b = bb + u;
                if (b < c){
                    unsigned int ub = zb[(st + b) * 64 + lane];
                    s[u] = a0 * bf16lo(ub) + a1 * bf16hi(ub);
                } else s[u] = 0.0f;
            }
            #pragma unroll
            for (int m = 1; m < 64; m <<= 1){
                s[0] += __shfl_xor(s[0], m);
                s[1] += __shfl_xor(s[1], m);
                s[2] += __shfl_xor(s[2], m);
                s[3] += __shfl_xor(s[3], m);
            }
            #pragma unroll
            for (int u = 0; u < 4; u++){
                int b = bb + u;
                if (b < c){
                    float e = exp2f(s[u]);
                    if (b == a){ if (lane == 0) selfs[st + a] = e; }
                    else pacc += e;
                }
            }
        }
        if (lane == 0) possum[st + a] = pacc;
    }
}

// K2: symmetric Gram row-sums. S = S^T, so enumerate only tile-pairs (ib <= jb) of
// 64x64 tiles: 8256 waves instead of 16384 — half the MFMA and half the exp work.
// Off-diagonal tiles contribute row sums to t[rows] AND column sums to t[cols]
// (E[j][i] = E[i][j]); diagonal tiles row sums only. One tile per wave = one short
// serial chain (loads -> 64 MFMA -> 64 exp) instead of a 16-iteration strip loop.
// Fragment: lane holds z[base+(lane&15)][ki*32 + (lane>>4)*8 .. +7]
// C layout: col = lane&15, row = quad*4 + r (within each 16x16 block).
__global__ __launch_bounds__(256) void k_gram(const unsigned short* __restrict__ z,
                                              float* __restrict__ t, int N){
    int tid  = threadIdx.x;
    int lane = tid & 63, w = tid >> 6;
    int quad = lane >> 4, l15 = lane & 15;
    int nb = N >> 6;
    int T  = nb * (nb + 1) / 2;
    int q  = blockIdx.x * 4 + w;
    if (q >= T) return;
    // triangle decode: largest r with r(r+1)/2 <= q  (fp seed + exact fixup)
    int r = (int)((sqrtf(8.0f * (float)q + 1.0f) - 1.0f) * 0.5f);
    while ((r + 1) * (r + 2) / 2 <= q) r++;
    while (r * (r + 1) / 2 > q) r--;
    int jb = r, ib = q - r * (r + 1) / 2;   // ib <= jb
    int r0 = ib * 64, c0 = jb * 64;
    size_t lq = (size_t)l15 * 128 + quad * 8;
    const unsigned short* za = z + (size_t)r0 * 128 + lq;
    const unsigned short* zc = z + (size_t)c0 * 128 + lq;

    // A fragments resident (16 x 16B loads); B streamed per k-step
    short8 af[4][4];
    #pragma unroll
    for (int mi = 0; mi < 4; mi++)
        #pragma unroll
        for (int ki = 0; ki < 4; ki++)
            af[mi][ki] = *(const short8*)(za + (size_t)(mi * 16) * 128 + ki * 32);

    float4v acc[4][4];
    #pragma unroll
    for (int mi = 0; mi < 4; mi++)
        #pragma unroll
        for (int ni = 0; ni < 4; ni++)
            acc[mi][ni] = (float4v){0.0f, 0.0f, 0.0f, 0.0f};

    #pragma unroll
    for (int ki = 0; ki < 4; ki++){
        short8 bfr[4];
        #pragma unroll
        for (int ni = 0; ni < 4; ni++)
            bfr[ni] = *(const short8*)(zc + (size_t)(ni * 16) * 128 + ki * 32);
        #pragma unroll
        for (int mi = 0; mi < 4; mi++)
            #pragma unroll
            for (int ni = 0; ni < 4; ni++)
                acc[mi][ni] = __builtin_amdgcn_mfma_f32_16x16x32_bf16(
                    af[mi][ki], bfr[ni], acc[mi][ni], 0, 0, 0);
    }

    // epilogue: e = exp2(dot); accumulate row partials and (off-diag) col partials
    float tsr[4][4];
    float tsc[4];
    #pragma unroll
    for (int mi = 0; mi < 4; mi++)
        #pragma unroll
        for (int rr = 0; rr < 4; rr++) tsr[mi][rr] = 0.0f;
    #pragma unroll
    for (int ni = 0; ni < 4; ni++) tsc[ni] = 0.0f;

    #pragma unroll
    for (int mi = 0; mi < 4; mi++)
        #pragma unroll
        for (int ni = 0; ni < 4; ni++)
            #pragma unroll
            for (int rr = 0; rr < 4; rr++){
                float e = exp2f(acc[mi][ni][rr]);
                tsr[mi][rr] += e;
                tsc[ni]     += e;
            }

    // row sums: reduce across the 16 col-lanes of the quad, atomic per row
    #pragma unroll
    for (int mi = 0; mi < 4; mi++)
        #pragma unroll
        for (int rr = 0; rr < 4; rr++){
            float v = tsr[mi][rr];
            v += __shfl_xor(v, 1);
            v += __shfl_xor(v, 2);
            v += __shfl_xor(v, 4);
            v += __shfl_xor(v, 8);
            if (l15 == 0) atomicAdd(&t[r0 + mi * 16 + quad * 4 + rr], v);
        }
    // col sums (transpose contribution), only for off-diagonal tiles:
    // reduce across quads (rows), lane l15 holds col ni*16+l15
    if (ib != jb){
        #pragma unroll
        for (int ni = 0; ni < 4; ni++){
            float v = tsc[ni];
            v += __shfl_xor(v, 16);
            v += __shfl_xor(v, 32);
            if (quad == 0) atomicAdd(&t[c0 + ni * 16 + l15], v);
        }
    }
}

// K3: loss = mean over rows of log(neg) - log(pos); neg = t - pos - self.
__global__ void k_final(const float* __restrict__ t, const float* __restrict__ possum,
                        const float* __restrict__ selfs, float* __restrict__ out, int N){
    int tid = threadIdx.x;
    int gid = blockIdx.x * 256 + tid;
    float s = 0.0f;
    if (gid < N){
        float p = possum[gid];
        float n = t[gid] - p - selfs[gid];
        s = logf(n) - logf(p);
    }
    #pragma unroll
    for (int m = 1; m < 64; m <<= 1) s += __shfl_xor(s, m);
    __shared__ float red[4];
    if ((tid & 63) == 0) red[tid >> 6] = s;
    __syncthreads();
    if (tid == 0) atomicAdd(out, (red[0] + red[1] + red[2] + red[3]) / (float)N);
}

extern "C" void kernel_launch(void* const* d_in, const int* in_sizes, int n_in,
                              void* d_out, int out_size, void* d_ws, size_t ws_size,
                              hipStream_t stream){
    const float* f  = (const float*)d_in[0];
    const int*   nc = (const int*)d_in[1];
    int N = in_sizes[0] / 128;   // 8192
    int G = in_sizes[1];         // 2048

    unsigned int* zb = (unsigned int*)d_ws;                       // N*256 B bf16 z (pre-scaled)
    float* t     = (float*)((char*)d_ws + (size_t)N * 256);       // N fp32
    float* pos   = t + N;
    float* selfs = pos + N;
    float* out   = (float*)d_out;

    k_prep<<<G, 64, 0, stream>>>(f, nc, zb, t, pos, selfs, out, G);
    int nb = N / 64;
    int T  = nb * (nb + 1) / 2;
    k_gram<<<(T + 3) / 4, 256, 0, stream>>>((const unsigned short*)zb, t, N);
    k_final<<<(N + 255) / 256, 256, 0, stream>>>(t, pos, selfs, out, N);
}